// Round 4
// baseline (572.759 us; speedup 1.0000x reference)
//
#include <hip/hip_runtime.h>
#include <hip/hip_bf16.h>

typedef __bf16 bf16;
typedef __attribute__((ext_vector_type(8)))  __bf16 bf16x8;
typedef __attribute__((ext_vector_type(4)))  __bf16 bf16x4;
typedef __attribute__((ext_vector_type(4)))  float  f32x4;

#define SEQ   2048
#define NDIM  256
#define NH3   48
#define CH    64
#define NG    16     // head groups (block handles heads g, g+16, g+32)
#define SKC   72     // sK row stride
#define SQC   72     // sQ/sP row stride (64 cols + pad)
#define SVJ   72     // sV row stride (64 j cols + pad)

// canonical bf16 input arena offsets (elements; all multiples of 8 -> 16B aligned)
#define OFF_NODES 0
#define OFF_POS   524288
#define OFF_ROT   536576
#define OFF_WN    544768
#define OFF_BN    1069056
#define OFF_WP    1071104
#define OFF_BP    1083392
#define OFF_WR    1085440
#define OFF_WV    1093632
#define OFF_BV    4239360
#define TOT_IN    4251648

__device__ bf16  g_in[TOT_IN];             // 8.5 MB canonical bf16 inputs
__device__ bf16  g_k [NH3 * SEQ * CH];     // [h][s][c] 12.6 MB
__device__ bf16  g_q [NH3 * SEQ * CH];     // [h][s][c] 12.6 MB
__device__ bf16  g_vt[NH3 * NDIM * SEQ];   // [h][d][j] 50.3 MB (transposed V)
__device__ float g_accg[NG * SEQ * NDIM];  // per-group fp32 partials, 33.6 MB
__device__ int   g_isf32;

// ---------------------------------------------------------------- dtype probe
// f32 data misread as bf16 has u16 halves with bf16-exponent 0xFF (p~1/256);
// f32 holding bf16-rounded values has even-index u16 == 0. True bf16: neither.
__global__ __launch_bounds__(256) void detect_k(const unsigned short* __restrict__ p) {
    __shared__ int cff, czero;
    if (threadIdx.x == 0) { cff = 0; czero = 0; }
    __syncthreads();
    int ff = 0, zz = 0;
    for (int r = 0; r < 64; ++r) {
        int idx = threadIdx.x * 64 + r;
        unsigned short u = p[idx];
        if (((u >> 7) & 0xFF) == 0xFF) ff++;
        if (((idx & 1) == 0) && (u == 0)) zz++;
    }
    if (ff) atomicAdd(&cff, ff);
    if (zz) atomicAdd(&czero, zz);
    __syncthreads();
    if (threadIdx.x == 0) g_isf32 = (cff > 2 || czero > 6000) ? 1 : 0;
}

// --------------------------------------------------------- input canonicalize
__global__ __launch_bounds__(256) void convert_k(
    const void* s0, const void* s1, const void* s2, const void* s3, const void* s4,
    const void* s5, const void* s6, const void* s7, const void* s8, const void* s9)
{
    const void* srcs[10] = {s0, s1, s2, s3, s4, s5, s6, s7, s8, s9};
    const int   szs[10]  = {524288, 12288, 8192, 524288, 2048, 12288, 2048, 8192, 3145728, 12288};
    const int   offs[10] = {OFF_NODES, OFF_POS, OFF_ROT, OFF_WN, OFF_BN,
                            OFF_WP, OFF_BP, OFF_WR, OFF_WV, OFF_BV};
    const int y = blockIdx.y;
    const void* src = srcs[y];
    bf16* dst = g_in + offs[y];
    const int n = szs[y];
    const int isf = g_isf32;
    const int stride = gridDim.x * 256 * 4;
    for (int i = (blockIdx.x * 256 + threadIdx.x) * 4; i < n; i += stride) {
        bf16x4 o;
        if (isf) {
            float4 v = *(const float4*)((const float*)src + i);
            o[0] = (bf16)v.x; o[1] = (bf16)v.y; o[2] = (bf16)v.z; o[3] = (bf16)v.w;
        } else {
            o = *(const bf16x4*)((const bf16*)src + i);
        }
        *(bf16x4*)(dst + i) = o;
    }
}

// ------------------------------------------------- nodes -> k,q (heads 0-15)
__global__ __launch_bounds__(256) void proj_nodes_kq()
{
    __shared__ __align__(16) bf16 sB[64 * 264];
    const bf16* nodes = g_in + OFF_NODES;
    const bf16* Wn    = g_in + OFF_WN;
    const bf16* bn    = g_in + OFF_BN;
    const int t  = threadIdx.x;
    const int s0 = blockIdx.x * 64;
    const int f0 = blockIdx.y * 64;

    for (int rep = 0; rep < 8; ++rep) {
        int idx = t + rep * 256;
        int row = idx >> 5, chunk = idx & 31;
        *(bf16x8*)&sB[row * 264 + chunk * 8] =
            *(const bf16x8*)&Wn[(f0 + row) * 256 + chunk * 8];
    }
    __syncthreads();

    const int w = t >> 6, lane = t & 63;
    const int l15 = lane & 15, quad = lane >> 4;

    f32x4 acc[4] = {{}, {}, {}, {}};
    const bf16* arow = nodes + (s0 + w * 16 + l15) * 256 + quad * 8;
#pragma unroll
    for (int kc = 0; kc < 8; ++kc) {
        bf16x8 af = *(const bf16x8*)(arow + kc * 32);
#pragma unroll
        for (int ft = 0; ft < 4; ++ft) {
            bf16x8 bfr = *(const bf16x8*)&sB[(ft * 16 + l15) * 264 + kc * 32 + quad * 8];
            acc[ft] = __builtin_amdgcn_mfma_f32_16x16x32_bf16(af, bfr, acc[ft], 0, 0, 0);
        }
    }
#pragma unroll
    for (int ft = 0; ft < 4; ++ft) {
        int f = f0 + ft * 16 + l15;
        float bias = (float)bn[f];
        int h = f >> 7, c2 = f & 127;
        bf16* base = (c2 < 64) ? (g_k + h * SEQ * CH + c2)
                               : (g_q + h * SEQ * CH + (c2 - 64));
#pragma unroll
        for (int r = 0; r < 4; ++r) {
            int s = s0 + w * 16 + quad * 4 + r;
            base[s * CH] = (bf16)(acc[ft][r] + bias);
        }
    }
}

// ------------------------------------- pos/rot -> k,q (heads 16-31 / 32-47)
__global__ __launch_bounds__(256) void proj_posrot_kq()
{
    const bf16* pos  = g_in + OFF_POS;
    const bf16* rotq = g_in + OFF_ROT;
    const bf16* Wp   = g_in + OFF_WP;
    const bf16* bp   = g_in + OFF_BP;
    const bf16* Wr   = g_in + OFF_WR;
    int id = blockIdx.x * 256 + threadIdx.x;
    int f  = id & 2047;
    int s  = (id >> 11) & 2047;
    int src = id >> 22;
    float y; int h;
    if (src == 0) {
        float a = (float)bp[f];
#pragma unroll
        for (int x = 0; x < 6; ++x) a += (float)pos[s * 6 + x] * (float)Wp[f * 6 + x];
        y = a; h = 16 + (f >> 7);
    } else {
        float a = 0.f;
#pragma unroll
        for (int x = 0; x < 4; ++x) a += (float)rotq[s * 4 + x] * (float)Wr[f * 4 + x];
        y = a; h = 32 + (f >> 7);
    }
    int c2 = f & 127;
    if (c2 < 64) g_k[(h * SEQ + s) * CH + c2]        = (bf16)y;
    else         g_q[(h * SEQ + s) * CH + (c2 - 64)] = (bf16)y;
}

// --------------------------------------------- nodes -> V (transposed store)
__global__ __launch_bounds__(256) void proj_v()
{
    __shared__ __align__(16) bf16 sB[64 * 264];
    const bf16* nodes = g_in + OFF_NODES;
    const bf16* Wv    = g_in + OFF_WV;
    const bf16* bv    = g_in + OFF_BV;
    const int t  = threadIdx.x;
    const int s0 = blockIdx.x * 64;
    const int f0 = blockIdx.y * 64;

    for (int rep = 0; rep < 8; ++rep) {
        int idx = t + rep * 256;
        int row = idx >> 5, chunk = idx & 31;
        *(bf16x8*)&sB[row * 264 + chunk * 8] =
            *(const bf16x8*)&Wv[(f0 + row) * 256 + chunk * 8];
    }
    __syncthreads();

    const int w = t >> 6, lane = t & 63;
    const int l15 = lane & 15, quad = lane >> 4;

    f32x4 acc[4] = {{}, {}, {}, {}};
    const bf16* arow = nodes + (s0 + w * 16 + l15) * 256 + quad * 8;
#pragma unroll
    for (int kc = 0; kc < 8; ++kc) {
        bf16x8 af = *(const bf16x8*)(arow + kc * 32);
#pragma unroll
        for (int ft = 0; ft < 4; ++ft) {
            bf16x8 bfr = *(const bf16x8*)&sB[(ft * 16 + l15) * 264 + kc * 32 + quad * 8];
            acc[ft] = __builtin_amdgcn_mfma_f32_16x16x32_bf16(af, bfr, acc[ft], 0, 0, 0);
        }
    }
#pragma unroll
    for (int ft = 0; ft < 4; ++ft) {
        int n = f0 + ft * 16 + l15;
        float bias = (float)bv[n];
        bf16x4 pv;
#pragma unroll
        for (int r = 0; r < 4; ++r) pv[r] = (bf16)(acc[ft][r] + bias);
        *(bf16x4*)&g_vt[n * SEQ + s0 + w * 16 + quad * 4] = pv;
    }
}

// ------------------------------------------------------------- attention
// grid (32 i-tiles, 16 groups); block loops heads {g, g+16, g+32}; per-head
// acc scaled by 1/l, folded into register total; plain stores per group.
__global__ __launch_bounds__(256) void attn_k()
{
    const int i0 = blockIdx.x * 64;
    const int g  = blockIdx.y;
    const int t  = threadIdx.x;
    const int w  = t >> 6, lane = t & 63;
    const int l15 = lane & 15, quad = lane >> 4;

    __shared__ __align__(16) bf16 sK[64 * SKC];     //  9216 B
    __shared__ __align__(16) bf16 sQP[64 * SQC];    //  9216 B (Q in S phase, P in PV phase)
    __shared__ __align__(16) bf16 sV[256 * SVJ];    // 36864 B
    __shared__ float sL[64];

    f32x4 tot[4][4];
#pragma unroll
    for (int a = 0; a < 4; ++a)
#pragma unroll
        for (int b = 0; b < 4; ++b) tot[a][b] = (f32x4){0.f, 0.f, 0.f, 0.f};

    for (int hh = 0; hh < 3; ++hh) {
        const int h = g + hh * 16;
        const bool rot_head = (hh == 2);
        const bf16* kb = g_k  + (h * SEQ + i0) * CH;
        const bf16* qb = g_q  + h * SEQ * CH;
        const bf16* vb = g_vt + h * NDIM * SEQ;

        __syncthreads();                     // prior head fully done with LDS
        for (int rep = 0; rep < 2; ++rep) {  // stage K tile (64 x 64)
            int idx = t + rep * 256;
            int row = idx >> 3, chunk = idx & 7;
            *(bf16x8*)&sK[row * SKC + chunk * 8] =
                *(const bf16x8*)&kb[row * CH + chunk * 8];
        }
        __syncthreads();
        bf16x8 kf0 = *(const bf16x8*)&sK[(w * 16 + l15) * SKC + quad * 8];
        bf16x8 kf1 = *(const bf16x8*)&sK[(w * 16 + l15) * SKC + 32 + quad * 8];

        f32x4 acc[4][4];
#pragma unroll
        for (int a = 0; a < 4; ++a)
#pragma unroll
            for (int b = 0; b < 4; ++b) acc[a][b] = (f32x4){0.f, 0.f, 0.f, 0.f};
        f32x4 lp = {0.f, 0.f, 0.f, 0.f};

        for (int j0 = 0; j0 < SEQ; j0 += 64) {
            __syncthreads();                      // prev PV done before restage
            for (int rep = 0; rep < 2; ++rep) {   // stage Q tile (64 x 64)
                int idx = t + rep * 256;
                int row = idx >> 3, chunk = idx & 7;
                *(bf16x8*)&sQP[row * SQC + chunk * 8] =
                    *(const bf16x8*)&qb[(j0 + row) * CH + chunk * 8];
            }
            for (int rep = 0; rep < 8; ++rep) {   // stage V^T tile (256 d x 64 j)
                int idx = t + rep * 256;
                int row = idx >> 3, chunk = idx & 7;
                *(bf16x8*)&sV[row * SVJ + chunk * 8] =
                    *(const bf16x8*)&vb[row * SEQ + j0 + chunk * 8];
            }
            __syncthreads();

            // S phase: wave w computes rows w*16..+16 x 64 j
            f32x4 sjb[4];
#pragma unroll
            for (int jb = 0; jb < 4; ++jb) {
                f32x4 sa = {};
                bf16x8 qf0 = *(const bf16x8*)&sQP[(jb * 16 + l15) * SQC + quad * 8];
                bf16x8 qf1 = *(const bf16x8*)&sQP[(jb * 16 + l15) * SQC + 32 + quad * 8];
                sa = __builtin_amdgcn_mfma_f32_16x16x32_bf16(kf0, qf0, sa, 0, 0, 0);
                sa = __builtin_amdgcn_mfma_f32_16x16x32_bf16(kf1, qf1, sa, 0, 0, 0);
                sjb[jb] = sa;
            }
            __syncthreads();                      // all waves done reading Q

            // P phase: p = exp(scale(s)) into sP rows [i][64 j], stride SQC
#pragma unroll
            for (int jb = 0; jb < 4; ++jb) {
#pragma unroll
                for (int r = 0; r < 4; ++r) {
                    float d = sjb[jb][r];
                    float x = rot_head ? (d * d * 0.25f) : (d * 0.25f);
                    x = fminf(x, 60.f);
                    float p = __expf(x);
                    lp[r] += p;
                    sQP[(w * 16 + quad * 4 + r) * SQC + jb * 16 + l15] = (bf16)p;
                }
            }
            __syncthreads();                      // sP ready

            // PV phase: wave w owns d-range w*64..+64; all 64 i rows
#pragma unroll
            for (int kc = 0; kc < 2; ++kc) {
                bf16x8 af[4], bfv[4];
#pragma unroll
                for (int it = 0; it < 4; ++it)
                    af[it] = *(const bf16x8*)&sQP[(it * 16 + l15) * SQC + kc * 32 + quad * 8];
#pragma unroll
                for (int dt = 0; dt < 4; ++dt)
                    bfv[dt] = *(const bf16x8*)&sV[(w * 64 + dt * 16 + l15) * SVJ + kc * 32 + quad * 8];
#pragma unroll
                for (int it = 0; it < 4; ++it)
#pragma unroll
                    for (int dt = 0; dt < 4; ++dt)
                        acc[it][dt] = __builtin_amdgcn_mfma_f32_16x16x32_bf16(
                            af[it], bfv[dt], acc[it][dt], 0, 0, 0);
            }
        }

        // reduce l over the 16 j-lanes, publish per-row l
#pragma unroll
        for (int off = 1; off < 16; off <<= 1) {
#pragma unroll
            for (int r = 0; r < 4; ++r) lp[r] += __shfl_xor(lp[r], off, 64);
        }
        if (l15 == 0) *(f32x4*)&sL[w * 16 + quad * 4] = lp;
        __syncthreads();

        // fold normalized head result into running total
#pragma unroll
        for (int it = 0; it < 4; ++it) {
            f32x4 lv = *(const f32x4*)&sL[it * 16 + quad * 4];
#pragma unroll
            for (int r = 0; r < 4; ++r) {
                float inv = 1.0f / lv[r];
#pragma unroll
                for (int dt = 0; dt < 4; ++dt)
                    tot[it][dt][r] += acc[it][dt][r] * inv;
            }
        }
    }

    // plain stores to this group's partial buffer
    float* ob = g_accg + (size_t)g * SEQ * NDIM;
#pragma unroll
    for (int it = 0; it < 4; ++it)
#pragma unroll
        for (int r = 0; r < 4; ++r) {
            int i = i0 + it * 16 + quad * 4 + r;
#pragma unroll
            for (int dt = 0; dt < 4; ++dt)
                ob[i * NDIM + w * 64 + dt * 16 + l15] = tot[it][dt][r];
        }
}

// --------------------------------------------- finalize: f32 OUTPUT (the fix)
__global__ __launch_bounds__(256) void finalize_k(float* __restrict__ out) {
    int idx = (blockIdx.x * 256 + threadIdx.x) * 4;
    f32x4 s = {0.f, 0.f, 0.f, 0.f};
#pragma unroll
    for (int gg = 0; gg < NG; ++gg) {
        f32x4 v = *(const f32x4*)&g_accg[(size_t)gg * SEQ * NDIM + idx];
        s += v;
    }
    *(f32x4*)&out[idx] = s;
}

extern "C" void kernel_launch(void* const* d_in, const int* in_sizes, int n_in,
                              void* d_out, int out_size, void* d_ws, size_t ws_size,
                              hipStream_t stream) {
    detect_k <<<dim3(1),        dim3(256), 0, stream>>>((const unsigned short*)d_in[8]);
    convert_k<<<dim3(768, 10),  dim3(256), 0, stream>>>(d_in[0], d_in[1], d_in[2], d_in[3],
                                                        d_in[4], d_in[5], d_in[6], d_in[7],
                                                        d_in[8], d_in[9]);
    proj_nodes_kq <<<dim3(32, 32),  dim3(256), 0, stream>>>();
    proj_posrot_kq<<<dim3(32768),   dim3(256), 0, stream>>>();
    proj_v        <<<dim3(32, 192), dim3(256), 0, stream>>>();
    attn_k        <<<dim3(32, 16),  dim3(256), 0, stream>>>();
    finalize_k    <<<dim3(512),     dim3(256), 0, stream>>>((float*)d_out);
}